// Round 1
// baseline (287.240 us; speedup 1.0000x reference)
//
#include <hip/hip_runtime.h>
#include <hip/hip_bf16.h>

// Sizes fixed by the problem.
#define BSZ 32768
#define NXD 512
#define NQD 128
#define NUD 64

typedef __attribute__((ext_vector_type(8))) unsigned short u16x8;
typedef __attribute__((ext_vector_type(8))) __bf16 bf16x8;
typedef __attribute__((ext_vector_type(4))) float f32x4;

#define DEVINL static __device__ __forceinline__

DEVINL unsigned short f2bf(float x) {
  __bf16 h = (__bf16)x;
  return __builtin_bit_cast(unsigned short, h);
}

DEVINL void gload_lds16(const ushort* g, ushort* l) {
  __builtin_amdgcn_global_load_lds(
      (const __attribute__((address_space(1))) void*)g,
      (__attribute__((address_space(3))) void*)l, 16, 0, 0);
}

DEVINL bf16x8 ld_frag(const ushort* p) {
  return __builtin_bit_cast(bf16x8, *(const u16x8*)p);
}

DEVINL float tanh_fast(float x) {
  x = fminf(fmaxf(x, -15.f), 15.f);
  float e = __expf(2.f * x);
  return 1.f - 2.f / (e + 1.f);
}

// ---------------------------------------------------------------------------
// Kernel 0a/0b: f32 -> bf16 vectorized convert (8 elems / thread)
// ---------------------------------------------------------------------------
__global__ __launch_bounds__(256) void cvt_bf16(const float* __restrict__ src,
                                                ushort* __restrict__ dst, int n8) {
  int i = blockIdx.x * 256 + threadIdx.x;
  if (i >= n8) return;
  const float4* s = (const float4*)src;
  float4 a = s[i * 2], b = s[i * 2 + 1];
  u16x8 v;
  v[0] = f2bf(a.x); v[1] = f2bf(a.y); v[2] = f2bf(a.z); v[3] = f2bf(a.w);
  v[4] = f2bf(b.x); v[5] = f2bf(b.y); v[6] = f2bf(b.z); v[7] = f2bf(b.w);
  *(u16x8*)(dst + (size_t)i * 8) = v;
}

// ---------------------------------------------------------------------------
// Kernel 0c: pack weights into K-contiguous bf16 panels
//   Wv[128][576]  row i = [C1[i,:512] | D12[i,:64]]
//   Wo[512][704]  row n = [A[n,:512] | B1[n,:128] | B2[n,:64]]
// ---------------------------------------------------------------------------
__global__ __launch_bounds__(256) void pack_weights(
    const float* __restrict__ A, const float* __restrict__ B1,
    const float* __restrict__ B2, const float* __restrict__ C1,
    const float* __restrict__ D12, ushort* __restrict__ Wv,
    ushort* __restrict__ Wo) {
  int f = blockIdx.x * 256 + threadIdx.x;
  const int NV = NQD * (NXD + NUD);  // 73728
  if (f < NV) {
    int i = f / (NXD + NUD);
    int k = f - i * (NXD + NUD);
    float v = (k < NXD) ? C1[i * NXD + k] : D12[i * NUD + (k - NXD)];
    Wv[f] = f2bf(v);
  } else {
    int f2 = f - NV;
    const int KO = NXD + NQD + NUD;  // 704
    if (f2 >= NXD * KO) return;
    int n = f2 / KO;
    int k = f2 - n * KO;
    float v;
    if (k < NXD)            v = A[n * NXD + k];
    else if (k < NXD + NQD) v = B1[n * NQD + (k - NXD)];
    else                    v = B2[n * NUD + (k - NXD - NQD)];
    Wo[f2] = f2bf(v);
  }
}

// ---------------------------------------------------------------------------
// bf16 GEMM (m97 structure): out[M][N] = Mseg @ W^T + bias
//   M operand = up to 3 row-major bf16 segments concatenated along K
//   W = [N][K] row-major bf16. Tile 128x128, BK=32, 256 thr (4 waves, 2x2),
//   each wave 64x64 via 4x4 mfma_f32_16x16x32_bf16 fragments.
// ---------------------------------------------------------------------------
__global__ __launch_bounds__(256) void gemm_bt(
    const ushort* __restrict__ p0, int e0, int ld0,
    const ushort* __restrict__ p1, int e1, int ld1,
    const ushort* __restrict__ p2, int ld2,
    const ushort* __restrict__ W, int K,
    const float* __restrict__ biasN,
    float* __restrict__ out, int ldo) {
  __shared__ ushort ldsA[128 * 32];
  __shared__ ushort ldsB[128 * 32];

  const int tid = threadIdx.x;
  const int lane = tid & 63;
  const int wv = tid >> 6;
  const int wm = wv >> 1, wn = wv & 1;
  const int rowBase = blockIdx.x * 128;
  const int colBase = blockIdx.y * 128;
  const int c8 = tid & 3;

  f32x4 acc[4][4];
#pragma unroll
  for (int m = 0; m < 4; ++m)
#pragma unroll
    for (int n = 0; n < 4; ++n) acc[m][n] = (f32x4){0.f, 0.f, 0.f, 0.f};

  const int KT = K >> 5;
  for (int kt = 0; kt < KT; ++kt) {
    const int k0 = kt << 5;
    // segment select (wave-uniform)
    const ushort* src;
    int kk, ld;
    if (k0 < e0)      { src = p0; kk = k0;      ld = ld0; }
    else if (k0 < e1) { src = p1; kk = k0 - e0; ld = ld1; }
    else              { src = p2; kk = k0 - e1; ld = ld2; }

    // stage A tile [128 rows][32 k] (8KB): 2 x global_load_lds_dwordx4
#pragma unroll
    for (int t = 0; t < 2; ++t) {
      int idx = t * 256 + tid;
      int r = idx >> 2;
      const ushort* g = src + (size_t)(rowBase + r) * ld + kk + c8 * 8;
      gload_lds16(g, ldsA + (size_t)idx * 8);
    }
    // stage B tile [128 rows][32 k]
#pragma unroll
    for (int t = 0; t < 2; ++t) {
      int idx = t * 256 + tid;
      int r = idx >> 2;
      const ushort* g = W + (size_t)(colBase + r) * K + k0 + c8 * 8;
      gload_lds16(g, ldsB + (size_t)idx * 8);
    }
    __syncthreads();

    const int frow = lane & 15;
    const int koff = (lane >> 4) * 8;
    bf16x8 af[4], bfr[4];
#pragma unroll
    for (int m = 0; m < 4; ++m)
      af[m] = ld_frag(ldsA + (wm * 64 + m * 16 + frow) * 32 + koff);
#pragma unroll
    for (int n = 0; n < 4; ++n)
      bfr[n] = ld_frag(ldsB + (wn * 64 + n * 16 + frow) * 32 + koff);

#pragma unroll
    for (int m = 0; m < 4; ++m)
#pragma unroll
      for (int n = 0; n < 4; ++n)
        acc[m][n] = __builtin_amdgcn_mfma_f32_16x16x32_bf16(af[m], bfr[n],
                                                            acc[m][n], 0, 0, 0);
    __syncthreads();
  }

  // epilogue: D layout col=lane&15, row=(lane>>4)*4+reg  [guide §3, verified]
  const int cl = lane & 15;
  const int rq = (lane >> 4) * 4;
#pragma unroll
  for (int m = 0; m < 4; ++m) {
    int row = rowBase + wm * 64 + m * 16 + rq;
#pragma unroll
    for (int n = 0; n < 4; ++n) {
      int col = colBase + wn * 64 + n * 16 + cl;
      float bn = biasN[col];
      float* o = out + (size_t)row * ldo + col;
#pragma unroll
      for (int j = 0; j < 4; ++j) o[(size_t)j * ldo] = acc[m][n][j] + bn;
    }
  }
}

// ---------------------------------------------------------------------------
// Kernel 2: forward substitution w[i] = tanh(base[i] + sum_{j<i} D11[i][j] w[j])
// 1 lane = 1 batch row; D11 (f32) broadcast from LDS; w[128] in registers,
// fully-unrolled triangular loop (all register indices compile-time).
// ---------------------------------------------------------------------------
__global__ __launch_bounds__(64) void recur(const float* __restrict__ base,
                                            const float* __restrict__ D11,
                                            ushort* __restrict__ wout) {
  __shared__ float ldsD[NQD * NQD];  // 64 KB
  const int tid = threadIdx.x;
  {
    const float4* s = (const float4*)D11;
    float4* d = (float4*)ldsD;
    for (int i = tid; i < NQD * NQD / 4; i += 64) d[i] = s[i];
  }
  __syncthreads();

  const int row = blockIdx.x * 64 + tid;
  const float* brow = base + (size_t)row * NQD;

  float w[NQD];
#pragma unroll
  for (int i = 0; i < NQD; ++i) w[i] = 0.f;  // safety: j>=i terms hit D11==0

#pragma unroll
  for (int i = 0; i < NQD; ++i) {
    float acc = brow[i];
    const float* dr = ldsD + (i << 7);
#pragma unroll
    for (int j = 0; j + 3 < i; j += 4) {
      float4 dv = *(const float4*)(dr + j);
      acc += dv.x * w[j] + dv.y * w[j + 1] + dv.z * w[j + 2] + dv.w * w[j + 3];
    }
#pragma unroll
    for (int j = i & ~3; j < i; ++j) acc += dr[j] * w[j];
    w[i] = tanh_fast(acc);
  }

  ushort* orow = wout + (size_t)row * NQD;
#pragma unroll
  for (int i = 0; i < NQD; i += 8) {
    u16x8 v;
#pragma unroll
    for (int j = 0; j < 8; ++j) v[j] = f2bf(w[i + j]);
    *(u16x8*)(orow + i) = v;
  }
}

// ---------------------------------------------------------------------------
extern "C" void kernel_launch(void* const* d_in, const int* in_sizes, int n_in,
                              void* d_out, int out_size, void* d_ws, size_t ws_size,
                              hipStream_t stream) {
  const float* xi  = (const float*)d_in[0];
  const float* u   = (const float*)d_in[1];
  const float* A   = (const float*)d_in[2];
  const float* B1  = (const float*)d_in[3];
  const float* B2  = (const float*)d_in[4];
  const float* C1  = (const float*)d_in[5];
  const float* D11 = (const float*)d_in[6];
  const float* D12 = (const float*)d_in[7];
  const float* bx  = (const float*)d_in[8];
  const float* bv  = (const float*)d_in[9];
  float* out = (float*)d_out;

  char* ws = (char*)d_ws;
  // ws layout (bytes), total ~60.8 MB
  ushort* xib  = (ushort*)(ws + 0);          // 32768*512*2  = 33554432
  ushort* ub   = (ushort*)(ws + 33554432);   // 32768*64*2   =  4194304
  ushort* wb   = (ushort*)(ws + 37748736);   // 32768*128*2  =  8388608
  float*  base = (float*)(ws + 46137344);    // 32768*128*4  = 16777216
  ushort* Wv   = (ushort*)(ws + 62914560);   // 128*576*2    =   147456
  ushort* Wo   = (ushort*)(ws + 63062016);   // 512*704*2    =   720896

  // converts
  cvt_bf16<<<dim3((BSZ * NXD / 8) / 256), 256, 0, stream>>>(xi, xib, BSZ * NXD / 8);
  cvt_bf16<<<dim3((BSZ * NUD / 8) / 256), 256, 0, stream>>>(u, ub, BSZ * NUD / 8);
  {
    int total = NQD * (NXD + NUD) + NXD * (NXD + NQD + NUD);  // 434176
    pack_weights<<<dim3((total + 255) / 256), 256, 0, stream>>>(A, B1, B2, C1,
                                                                D12, Wv, Wo);
  }

  // base = [xi|u] @ [C1|D12]^T + bv   (K=576, N=128)
  gemm_bt<<<dim3(BSZ / 128, 1), 256, 0, stream>>>(
      xib, NXD, NXD, ub, NXD + NUD, NUD, ub, NUD, Wv, NXD + NUD, bv, base, NQD);

  // w = forward substitution + tanh
  recur<<<dim3(BSZ / 64), 64, 0, stream>>>(base, D11, wb);

  // out = [xi|w|u] @ [A|B1|B2]^T + bx   (K=704, N=512)
  gemm_bt<<<dim3(BSZ / 128, 4), 256, 0, stream>>>(
      xib, NXD, NXD, wb, NXD + NQD, NQD, ub, NUD, Wo, NXD + NQD + NUD, bx, out,
      NXD);
}

// Round 2
// 229.948 us; speedup vs baseline: 1.2492x; 1.2492x over previous
//
#include <hip/hip_runtime.h>
#include <hip/hip_bf16.h>

// Sizes fixed by the problem.
#define BSZ 32768
#define NXD 512
#define NQD 128
#define NUD 64

typedef __attribute__((ext_vector_type(8))) unsigned short u16x8;
typedef __attribute__((ext_vector_type(8))) __bf16 bf16x8;
typedef __attribute__((ext_vector_type(4))) float f32x4;

#define DEVINL static __device__ __forceinline__

DEVINL unsigned short f2bf(float x) {
  __bf16 h = (__bf16)x;
  return __builtin_bit_cast(unsigned short, h);
}

DEVINL void gload_lds16(const ushort* g, ushort* l) {
  __builtin_amdgcn_global_load_lds(
      (const __attribute__((address_space(1))) void*)g,
      (__attribute__((address_space(3))) void*)l, 16, 0, 0);
}

DEVINL bf16x8 ld_frag(const ushort* p) {
  return __builtin_bit_cast(bf16x8, *(const u16x8*)p);
}

DEVINL float tanh_fast(float x) {
  x = fminf(fmaxf(x, -15.f), 15.f);
  float e = __expf(2.f * x);
  return 1.f - 2.f / (e + 1.f);
}

// ---------------------------------------------------------------------------
// f32 -> bf16 vectorized convert (8 elems / thread)
// ---------------------------------------------------------------------------
__global__ __launch_bounds__(256) void cvt_bf16(const float* __restrict__ src,
                                                ushort* __restrict__ dst, int n8) {
  int i = blockIdx.x * 256 + threadIdx.x;
  if (i >= n8) return;
  const float4* s = (const float4*)src;
  float4 a = s[i * 2], b = s[i * 2 + 1];
  u16x8 v;
  v[0] = f2bf(a.x); v[1] = f2bf(a.y); v[2] = f2bf(a.z); v[3] = f2bf(a.w);
  v[4] = f2bf(b.x); v[5] = f2bf(b.y); v[6] = f2bf(b.z); v[7] = f2bf(b.w);
  *(u16x8*)(dst + (size_t)i * 8) = v;
}

// ---------------------------------------------------------------------------
// pack weights into K-contiguous bf16 panels + f32 transposed D11
//   Wv[128][576]  row i = [C1[i,:512] | D12[i,:64]]
//   Wo[512][704]  row n = [A[n,:512] | B1[n,:128] | B2[n,:64]]
//   Dt[128][128]  Dt[j][i] = D11[i][j]   (f32)
// ---------------------------------------------------------------------------
__global__ __launch_bounds__(256) void pack_weights(
    const float* __restrict__ A, const float* __restrict__ B1,
    const float* __restrict__ B2, const float* __restrict__ C1,
    const float* __restrict__ D11, const float* __restrict__ D12,
    ushort* __restrict__ Wv, ushort* __restrict__ Wo,
    float* __restrict__ Dt) {
  int f = blockIdx.x * 256 + threadIdx.x;
  const int NV = NQD * (NXD + NUD);      // 73728
  const int KO = NXD + NQD + NUD;        // 704
  const int NO = NXD * KO;               // 360448
  if (f < NV) {
    int i = f / (NXD + NUD);
    int k = f - i * (NXD + NUD);
    float v = (k < NXD) ? C1[i * NXD + k] : D12[i * NUD + (k - NXD)];
    Wv[f] = f2bf(v);
  } else if (f < NV + NO) {
    int f2 = f - NV;
    int n = f2 / KO;
    int k = f2 - n * KO;
    float v;
    if (k < NXD)            v = A[n * NXD + k];
    else if (k < NXD + NQD) v = B1[n * NQD + (k - NXD)];
    else                    v = B2[n * NUD + (k - NXD - NQD)];
    Wo[f2] = f2bf(v);
  } else {
    int f3 = f - NV - NO;
    if (f3 >= NQD * NQD) return;
    int j = f3 >> 7, i = f3 & (NQD - 1);
    Dt[f3] = D11[i * NQD + j];
  }
}

// ---------------------------------------------------------------------------
// bf16 GEMM (m97 structure): out[M][N] = Mseg @ W^T + bias
//   M operand = up to 3 row-major bf16 segments concatenated along K
//   W = [N][K] row-major bf16. Tile 128x128, BK=32, 256 thr (4 waves, 2x2),
//   each wave 64x64 via 4x4 mfma_f32_16x16x32_bf16 fragments.
// ---------------------------------------------------------------------------
__global__ __launch_bounds__(256) void gemm_bt(
    const ushort* __restrict__ p0, int e0, int ld0,
    const ushort* __restrict__ p1, int e1, int ld1,
    const ushort* __restrict__ p2, int ld2,
    const ushort* __restrict__ W, int K,
    const float* __restrict__ biasN,
    float* __restrict__ out, int ldo) {
  __shared__ ushort ldsA[128 * 32];
  __shared__ ushort ldsB[128 * 32];

  const int tid = threadIdx.x;
  const int lane = tid & 63;
  const int wv = tid >> 6;
  const int wm = wv >> 1, wn = wv & 1;
  const int rowBase = blockIdx.x * 128;
  const int colBase = blockIdx.y * 128;
  const int c8 = tid & 3;

  f32x4 acc[4][4];
#pragma unroll
  for (int m = 0; m < 4; ++m)
#pragma unroll
    for (int n = 0; n < 4; ++n) acc[m][n] = (f32x4){0.f, 0.f, 0.f, 0.f};

  const int KT = K >> 5;
  for (int kt = 0; kt < KT; ++kt) {
    const int k0 = kt << 5;
    const ushort* src;
    int kk, ld;
    if (k0 < e0)      { src = p0; kk = k0;      ld = ld0; }
    else if (k0 < e1) { src = p1; kk = k0 - e0; ld = ld1; }
    else              { src = p2; kk = k0 - e1; ld = ld2; }

#pragma unroll
    for (int t = 0; t < 2; ++t) {
      int idx = t * 256 + tid;
      int r = idx >> 2;
      const ushort* g = src + (size_t)(rowBase + r) * ld + kk + c8 * 8;
      gload_lds16(g, ldsA + (size_t)idx * 8);
    }
#pragma unroll
    for (int t = 0; t < 2; ++t) {
      int idx = t * 256 + tid;
      int r = idx >> 2;
      const ushort* g = W + (size_t)(colBase + r) * K + k0 + c8 * 8;
      gload_lds16(g, ldsB + (size_t)idx * 8);
    }
    __syncthreads();

    const int frow = lane & 15;
    const int koff = (lane >> 4) * 8;
    bf16x8 af[4], bfr[4];
#pragma unroll
    for (int m = 0; m < 4; ++m)
      af[m] = ld_frag(ldsA + (wm * 64 + m * 16 + frow) * 32 + koff);
#pragma unroll
    for (int n = 0; n < 4; ++n)
      bfr[n] = ld_frag(ldsB + (wn * 64 + n * 16 + frow) * 32 + koff);

#pragma unroll
    for (int m = 0; m < 4; ++m)
#pragma unroll
      for (int n = 0; n < 4; ++n)
        acc[m][n] = __builtin_amdgcn_mfma_f32_16x16x32_bf16(af[m], bfr[n],
                                                            acc[m][n], 0, 0, 0);
    __syncthreads();
  }

  const int cl = lane & 15;
  const int rq = (lane >> 4) * 4;
#pragma unroll
  for (int m = 0; m < 4; ++m) {
    int row = rowBase + wm * 64 + m * 16 + rq;
#pragma unroll
    for (int n = 0; n < 4; ++n) {
      int col = colBase + wn * 64 + n * 16 + cl;
      float bn = biasN[col];
      float* o = out + (size_t)row * ldo + col;
#pragma unroll
      for (int j = 0; j < 4; ++j) o[(size_t)j * ldo] = acc[m][n][j] + bn;
    }
  }
}

// ---------------------------------------------------------------------------
// Forward substitution, column-sweep, 8 lanes per batch row.
//   w[j] = tanh(acc[j]);  acc[i] += Dt[j][i] * w[j]  (Dt = D11^T, zero for i<=j)
// Lane (s = lane&7) owns acc rows i = s*16 .. s*16+15 in registers.
// 512 threads = 8 waves = 64 batch rows / block; grid 512 blocks.
// LDS: Dt in permuted chunk layout so the 8 slices' ds_read_b128 per step
// land on banks 4s..4s+3 (conflict-free):
//   element i = s*16 + q*4 + e of row j  ->  float4 chunk [j*32 + q*8 + s]
// ---------------------------------------------------------------------------
__global__ __launch_bounds__(512) void recur2(const float* __restrict__ base,
                                              const float* __restrict__ Dt,
                                              ushort* __restrict__ wout) {
  __shared__ float ldsD[NQD * NQD];  // 64 KB
  const int tid = threadIdx.x;

  // stage Dt -> LDS with chunk permutation (coalesced global reads)
  for (int c = tid; c < NQD * NQD / 4; c += 512) {
    int j = c >> 5, cg = c & 31;
    int s = cg >> 2, q = cg & 3;
    float4 v = ((const float4*)Dt)[c];
    ((float4*)ldsD)[j * 32 + q * 8 + s] = v;
  }
  __syncthreads();

  const int lane = tid & 63;
  const int wid = tid >> 6;
  const int s = lane & 7;
  const int row = blockIdx.x * 64 + wid * 8 + (lane >> 3);

  float acc[16];
  {
    const float4* bp4 = (const float4*)(base + (size_t)row * NQD + s * 16);
    float4 a0 = bp4[0], a1 = bp4[1], a2 = bp4[2], a3 = bp4[3];
    acc[0] = a0.x;  acc[1] = a0.y;  acc[2] = a0.z;  acc[3] = a0.w;
    acc[4] = a1.x;  acc[5] = a1.y;  acc[6] = a1.z;  acc[7] = a1.w;
    acc[8] = a2.x;  acc[9] = a2.y;  acc[10] = a2.z; acc[11] = a2.w;
    acc[12] = a3.x; acc[13] = a3.y; acc[14] = a3.z; acc[15] = a3.w;
  }

  float wl[16];
#pragma unroll
  for (int t = 0; t < 16; ++t) wl[t] = 0.f;

  const float4* ldsD4 = (const float4*)ldsD;

  for (int jb = 0; jb < 8; ++jb) {          // runtime outer loop (I-cache)
    const int ownerLane = (lane & 56) | jb; // g*8 + jb
    const bool own = (s == jb);
#pragma unroll
    for (int jj = 0; jj < 16; ++jj) {       // compile-time register indices
      const int j16 = jj;                   // acc index (== j & 15)
      float tv = tanh_fast(acc[j16]);       // valid on owner lane; others unused
      float wj = __shfl(tv, ownerLane, 64);
      if (own) wl[j16] = wj;
      const int jrow = (jb * 16 + jj) * 32;
      float4 d0 = ldsD4[jrow + s];
      float4 d1 = ldsD4[jrow + 8 + s];
      float4 d2 = ldsD4[jrow + 16 + s];
      float4 d3 = ldsD4[jrow + 24 + s];
      acc[0]  += d0.x * wj; acc[1]  += d0.y * wj;
      acc[2]  += d0.z * wj; acc[3]  += d0.w * wj;
      acc[4]  += d1.x * wj; acc[5]  += d1.y * wj;
      acc[6]  += d1.z * wj; acc[7]  += d1.w * wj;
      acc[8]  += d2.x * wj; acc[9]  += d2.y * wj;
      acc[10] += d2.z * wj; acc[11] += d2.w * wj;
      acc[12] += d3.x * wj; acc[13] += d3.y * wj;
      acc[14] += d3.z * wj; acc[15] += d3.w * wj;
    }
  }

  // lane owns w[s*16 .. s*16+15] for its batch row
  ushort* orow = wout + (size_t)row * NQD + s * 16;
  u16x8 v0, v1;
#pragma unroll
  for (int t = 0; t < 8; ++t) { v0[t] = f2bf(wl[t]); v1[t] = f2bf(wl[t + 8]); }
  *(u16x8*)orow = v0;
  *(u16x8*)(orow + 8) = v1;
}

// ---------------------------------------------------------------------------
extern "C" void kernel_launch(void* const* d_in, const int* in_sizes, int n_in,
                              void* d_out, int out_size, void* d_ws, size_t ws_size,
                              hipStream_t stream) {
  const float* xi  = (const float*)d_in[0];
  const float* u   = (const float*)d_in[1];
  const float* A   = (const float*)d_in[2];
  const float* B1  = (const float*)d_in[3];
  const float* B2  = (const float*)d_in[4];
  const float* C1  = (const float*)d_in[5];
  const float* D11 = (const float*)d_in[6];
  const float* D12 = (const float*)d_in[7];
  const float* bx  = (const float*)d_in[8];
  const float* bv  = (const float*)d_in[9];
  float* out = (float*)d_out;

  char* ws = (char*)d_ws;
  // ws layout (bytes)
  ushort* xib  = (ushort*)(ws + 0);          // 32768*512*2  = 33554432
  ushort* ub   = (ushort*)(ws + 33554432);   // 32768*64*2   =  4194304
  ushort* wb   = (ushort*)(ws + 37748736);   // 32768*128*2  =  8388608
  float*  base = (float*)(ws + 46137344);    // 32768*128*4  = 16777216
  ushort* Wv   = (ushort*)(ws + 62914560);   // 128*576*2    =   147456
  ushort* Wo   = (ushort*)(ws + 63062016);   // 512*704*2    =   720896
  float*  Dt   = (float*)(ws + 63782912);    // 128*128*4    =    65536

  cvt_bf16<<<dim3((BSZ * NXD / 8) / 256), 256, 0, stream>>>(xi, xib, BSZ * NXD / 8);
  cvt_bf16<<<dim3((BSZ * NUD / 8) / 256), 256, 0, stream>>>(u, ub, BSZ * NUD / 8);
  {
    int total = NQD * (NXD + NUD) + NXD * (NXD + NQD + NUD) + NQD * NQD;
    pack_weights<<<dim3((total + 255) / 256), 256, 0, stream>>>(
        A, B1, B2, C1, D11, D12, Wv, Wo, Dt);
  }

  // base = [xi|u] @ [C1|D12]^T + bv   (K=576, N=128)
  gemm_bt<<<dim3(BSZ / 128, 1), 256, 0, stream>>>(
      xib, NXD, NXD, ub, NXD + NUD, NUD, ub, NUD, Wv, NXD + NUD, bv, base, NQD);

  // w = forward substitution + tanh (column sweep, 8 lanes/row)
  recur2<<<dim3(BSZ / 64), 512, 0, stream>>>(base, Dt, wb);

  // out = [xi|w|u] @ [A|B1|B2]^T + bx   (K=704, N=512)
  gemm_bt<<<dim3(BSZ / 128, 4), 256, 0, stream>>>(
      xib, NXD, NXD, wb, NXD + NQD, NQD, ub, NUD, Wo, NXD + NQD + NUD, bx, out,
      NXD);
}

// Round 5
// 229.260 us; speedup vs baseline: 1.2529x; 1.0030x over previous
//
#include <hip/hip_runtime.h>
#include <hip/hip_bf16.h>

// Sizes fixed by the problem.
#define BSZ 32768
#define NXD 512
#define NQD 128
#define NUD 64

typedef __attribute__((ext_vector_type(8))) unsigned short u16x8;
typedef __attribute__((ext_vector_type(8))) __bf16 bf16x8;
typedef __attribute__((ext_vector_type(4))) float f32x4;

#define DEVINL static __device__ __forceinline__

DEVINL unsigned short f2bf(float x) {
  __bf16 h = (__bf16)x;
  return __builtin_bit_cast(unsigned short, h);
}

DEVINL void gload_lds16(const ushort* g, ushort* l) {
  __builtin_amdgcn_global_load_lds(
      (const __attribute__((address_space(1))) void*)g,
      (__attribute__((address_space(3))) void*)l, 16, 0, 0);
}

DEVINL bf16x8 ld_frag(const ushort* p) {
  return __builtin_bit_cast(bf16x8, *(const u16x8*)p);
}

DEVINL float tanh_fast(float x) {
  x = fminf(fmaxf(x, -15.f), 15.f);
  float e = __expf(2.f * x);
  return 1.f - 2.f / (e + 1.f);
}

// ---------------------------------------------------------------------------
// prep: fused f32->bf16 converts + weight packing + D11 transpose.
//   xib[32768][512], ub[32768][64]           (bf16)
//   Wv[128][576]  row i = [C1[i] | D12[i]]   (bf16)
//   Wo[512][704]  row n = [A[n] | B1[n] | B2[n]] (bf16)
//   Dt[128][128]  Dt[j][i] = D11[i][j]       (f32)
// ---------------------------------------------------------------------------
DEVINL void cvt8(const float* src, ushort* dst, int i) {
  const float4* s = (const float4*)src;
  float4 a = s[i * 2], b = s[i * 2 + 1];
  u16x8 v;
  v[0] = f2bf(a.x); v[1] = f2bf(a.y); v[2] = f2bf(a.z); v[3] = f2bf(a.w);
  v[4] = f2bf(b.x); v[5] = f2bf(b.y); v[6] = f2bf(b.z); v[7] = f2bf(b.w);
  *(u16x8*)(dst + (size_t)i * 8) = v;
}

__global__ __launch_bounds__(256) void prep(
    const float* __restrict__ xi, const float* __restrict__ u,
    const float* __restrict__ A, const float* __restrict__ B1,
    const float* __restrict__ B2, const float* __restrict__ C1,
    const float* __restrict__ D11, const float* __restrict__ D12,
    ushort* __restrict__ xib, ushort* __restrict__ ub,
    ushort* __restrict__ Wv, ushort* __restrict__ Wo,
    float* __restrict__ Dt) {
  int idx = blockIdx.x * 256 + threadIdx.x;
  const int N0 = BSZ * NXD / 8;            // 2097152  xi convert (8-wide)
  const int N1 = N0 + BSZ * NUD / 8;       // + 262144 u convert (8-wide)
  const int N2 = N1 + NQD * (NXD + NUD);   // + 73728  Wv
  const int N3 = N2 + NXD * 704;           // + 360448 Wo
  const int N4 = N3 + NQD * NQD;           // + 16384  Dt
  if (idx < N0) {
    cvt8(xi, xib, idx);
  } else if (idx < N1) {
    cvt8(u, ub, idx - N0);
  } else if (idx < N2) {
    int f = idx - N1;
    int i = f / (NXD + NUD);
    int k = f - i * (NXD + NUD);
    Wv[f] = f2bf(k < NXD ? C1[i * NXD + k] : D12[i * NUD + (k - NXD)]);
  } else if (idx < N3) {
    int f = idx - N2;
    int n = f / 704;
    int k = f - n * 704;
    float v;
    if (k < NXD)            v = A[n * NXD + k];
    else if (k < NXD + NQD) v = B1[n * NQD + (k - NXD)];
    else                    v = B2[n * NUD + (k - NXD - NQD)];
    Wo[f] = f2bf(v);
  } else if (idx < N4) {
    int f = idx - N3;
    int j = f >> 7, i = f & (NQD - 1);
    Dt[f] = D11[i * NQD + j];
  }
}

// ---------------------------------------------------------------------------
// bf16 GEMM, 2-phase double-buffered, BK=64, T2 XOR-swizzled LDS.
//   out[M][N] = Mseg @ W^T + bias
//   A operand: up to 3 row-major bf16 segments concatenated along K
//     (all segment boundaries are multiples of BK=64).
//   W: [N][K] row-major bf16.
//   Swizzle (rule #21): LDS dest linear for global_load_lds; the global
//   SOURCE column is pre-permuted (slot ^ row&7), ds_read applies the same
//   XOR -> frag reads are 2-way conflicts (free).
// ---------------------------------------------------------------------------
template <int BM, int BN, int WM, int WN>
__global__ __launch_bounds__(WM* WN * 64, 2) void gemm2ph(
    const ushort* __restrict__ p0, int e0, int ld0,
    const ushort* __restrict__ p1, int e1, int ld1,
    const ushort* __restrict__ p2, int ld2,
    const ushort* __restrict__ W, int K,
    const float* __restrict__ biasN,
    float* __restrict__ out, int ldo) {
  constexpr int THREADS = WM * WN * 64;
  constexpr int BK = 64;
  constexpr int MREP = BM / WM / 16;
  constexpr int NREP = BN / WN / 16;
  constexpr int PASSA = BM * 8 / THREADS;
  constexpr int PASSB = BN * 8 / THREADS;

  __shared__ ushort ldsA[2][BM * BK];
  __shared__ ushort ldsB[2][BN * BK];

  const int tid = threadIdx.x;
  const int lane = tid & 63;
  const int wv = tid >> 6;
  const int wm = wv / WN, wn = wv % WN;
  const int rowBase = blockIdx.x * BM;
  const int colBase = blockIdx.y * BN;

  f32x4 acc[MREP][NREP];
#pragma unroll
  for (int m = 0; m < MREP; ++m)
#pragma unroll
    for (int n = 0; n < NREP; ++n) acc[m][n] = (f32x4){0.f, 0.f, 0.f, 0.f};

  const int NT = K / BK;

  auto stage = [&](int b, int kt) {
    const int k0 = kt * BK;
    const ushort* src; int kk, ld;
    if (k0 < e0)      { src = p0; kk = k0;      ld = ld0; }
    else if (k0 < e1) { src = p1; kk = k0 - e0; ld = ld1; }
    else              { src = p2; kk = k0 - e1; ld = ld2; }
#pragma unroll
    for (int p = 0; p < PASSA; ++p) {
      int idx = p * THREADS + tid;
      int row = idx >> 3, slot = idx & 7;
      int gcol = kk + ((slot ^ (row & 7)) << 3);
      gload_lds16(src + (size_t)(rowBase + row) * ld + gcol,
                  &ldsA[b][idx * 8]);
    }
#pragma unroll
    for (int p = 0; p < PASSB; ++p) {
      int idx = p * THREADS + tid;
      int row = idx >> 3, slot = idx & 7;
      int gcol = k0 + ((slot ^ (row & 7)) << 3);
      gload_lds16(W + (size_t)(colBase + row) * K + gcol, &ldsB[b][idx * 8]);
    }
  };

  stage(0, 0);
  __syncthreads();  // drains vmcnt -> buf0 ready

  int cur = 0;
  for (int kt = 0; kt < NT; ++kt) {
    if (kt + 1 < NT) stage(cur ^ 1, kt + 1);  // prefetch under compute

#pragma unroll
    for (int ks = 0; ks < 2; ++ks) {
      bf16x8 af[MREP], bfr[NREP];
#pragma unroll
      for (int m = 0; m < MREP; ++m) {
        int r = wm * (BM / WM) + m * 16 + (lane & 15);
        int slot = (ks * 4 + (lane >> 4)) ^ (r & 7);
        af[m] = ld_frag(&ldsA[cur][r * BK + slot * 8]);
      }
#pragma unroll
      for (int n = 0; n < NREP; ++n) {
        int r = wn * (BN / WN) + n * 16 + (lane & 15);
        int slot = (ks * 4 + (lane >> 4)) ^ (r & 7);
        bfr[n] = ld_frag(&ldsB[cur][r * BK + slot * 8]);
      }
#pragma unroll
      for (int m = 0; m < MREP; ++m)
#pragma unroll
        for (int n = 0; n < NREP; ++n)
          acc[m][n] = __builtin_amdgcn_mfma_f32_16x16x32_bf16(
              af[m], bfr[n], acc[m][n], 0, 0, 0);
    }
    __syncthreads();  // all reads of buf[cur] done; prefetch drained
    cur ^= 1;
  }

  // epilogue: C/D layout col=lane&15, row=(lane>>4)*4+j
  const int cl = lane & 15;
  const int rq = (lane >> 4) * 4;
#pragma unroll
  for (int m = 0; m < MREP; ++m) {
    int row = rowBase + wm * (BM / WM) + m * 16 + rq;
#pragma unroll
    for (int n = 0; n < NREP; ++n) {
      int col = colBase + wn * (BN / WN) + n * 16 + cl;
      float bn = biasN[col];
      float* o = out + (size_t)row * ldo + col;
#pragma unroll
      for (int j = 0; j < 4; ++j) o[(size_t)j * ldo] = acc[m][n][j] + bn;
    }
  }
}

// ---------------------------------------------------------------------------
// Forward substitution, column-sweep, 16 lanes per batch row.
//   w[j] = tanh(acc[j]);  acc[i] += Dt[j][i] * w[j]   (Dt strictly upper)
// Lane s = lane&15 owns acc rows i = s*8 .. s*8+7 (8 regs).
// 512 thr = 8 waves = 32 rows/block; grid 1024; LDS 64KB -> 2 blocks/CU.
// Dt chunk c (=i/4) of row j stored at slot perm(c) = (c&1)*16 + (c>>1):
// per step lane reads slots {s} and {16+s} -> each read 2-way max (free).
// ---------------------------------------------------------------------------
__global__ __launch_bounds__(512) void recur16(const float* __restrict__ base,
                                               const float* __restrict__ Dt,
                                               ushort* __restrict__ wout) {
  __shared__ float ldsD[NQD * NQD];  // 64 KB
  const int tid = threadIdx.x;

  for (int c = tid; c < NQD * NQD / 4; c += 512) {
    int j = c >> 5, ch = c & 31;
    int slot = ((ch & 1) << 4) | (ch >> 1);
    ((float4*)ldsD)[j * 32 + slot] = ((const float4*)Dt)[c];
  }
  __syncthreads();

  const int lane = tid & 63;
  const int wid = tid >> 6;
  const int s = lane & 15;
  const int g = lane >> 4;  // 4 rows per wave
  const int row = blockIdx.x * 32 + wid * 4 + g;

  float acc[8];
  {
    const float4* bp4 = (const float4*)(base + (size_t)row * NQD + s * 8);
    float4 a0 = bp4[0], a1 = bp4[1];
    acc[0] = a0.x; acc[1] = a0.y; acc[2] = a0.z; acc[3] = a0.w;
    acc[4] = a1.x; acc[5] = a1.y; acc[6] = a1.z; acc[7] = a1.w;
  }
  float wl[8];
#pragma unroll
  for (int t = 0; t < 8; ++t) wl[t] = 0.f;

  const float4* ldsD4 = (const float4*)ldsD;

  for (int jb = 0; jb < 16; ++jb) {          // owner lane sweep
    const int ownerLane = (g << 4) | jb;
    const bool own = (s == jb);
#pragma unroll
    for (int jj = 0; jj < 8; ++jj) {         // compile-time register indices
      float tv = tanh_fast(acc[jj]);         // valid on owner lane
      float wj = __shfl(tv, ownerLane, 64);
      if (own) wl[jj] = wj;
      const int jrow = (jb * 8 + jj) * 32;
      float4 d0 = ldsD4[jrow + s];
      float4 d1 = ldsD4[jrow + 16 + s];
      acc[0] += d0.x * wj; acc[1] += d0.y * wj;
      acc[2] += d0.z * wj; acc[3] += d0.w * wj;
      acc[4] += d1.x * wj; acc[5] += d1.y * wj;
      acc[6] += d1.z * wj; acc[7] += d1.w * wj;
    }
  }

  ushort* orow = wout + (size_t)row * NQD + s * 8;
  u16x8 v;
#pragma unroll
  for (int t = 0; t < 8; ++t) v[t] = f2bf(wl[t]);
  *(u16x8*)orow = v;
}

// ---------------------------------------------------------------------------
extern "C" void kernel_launch(void* const* d_in, const int* in_sizes, int n_in,
                              void* d_out, int out_size, void* d_ws, size_t ws_size,
                              hipStream_t stream) {
  const float* xi  = (const float*)d_in[0];
  const float* u   = (const float*)d_in[1];
  const float* A   = (const float*)d_in[2];
  const float* B1  = (const float*)d_in[3];
  const float* B2  = (const float*)d_in[4];
  const float* C1  = (const float*)d_in[5];
  const float* D11 = (const float*)d_in[6];
  const float* D12 = (const float*)d_in[7];
  const float* bx  = (const float*)d_in[8];
  const float* bv  = (const float*)d_in[9];
  float* out = (float*)d_out;

  char* ws = (char*)d_ws;
  ushort* xib  = (ushort*)(ws + 0);          // 32768*512*2  = 33554432
  ushort* ub   = (ushort*)(ws + 33554432);   // 32768*64*2   =  4194304
  ushort* wb   = (ushort*)(ws + 37748736);   // 32768*128*2  =  8388608
  float*  base = (float*)(ws + 46137344);    // 32768*128*4  = 16777216
  ushort* Wv   = (ushort*)(ws + 62914560);   // 128*576*2    =   147456
  ushort* Wo   = (ushort*)(ws + 63062016);   // 512*704*2    =   720896
  float*  Dt   = (float*)(ws + 63782912);    // 128*128*4    =    65536

  {
    int total = BSZ * NXD / 8 + BSZ * NUD / 8 + NQD * (NXD + NUD) + NXD * 704 +
                NQD * NQD;
    prep<<<dim3((total + 255) / 256), 256, 0, stream>>>(
        xi, u, A, B1, B2, C1, D11, D12, xib, ub, Wv, Wo, Dt);
  }

  // base = [xi|u] @ [C1|D12]^T + bv   (K=576, N=128), 128x128 tile
  gemm2ph<128, 128, 2, 2><<<dim3(BSZ / 128, 1), 256, 0, stream>>>(
      xib, NXD, NXD, ub, NXD + NUD, NUD, ub, NUD, Wv, NXD + NUD, bv, base, NQD);

  // w = forward substitution + tanh (column sweep, 16 lanes/row)
  recur16<<<dim3(BSZ / 32), 512, 0, stream>>>(base, Dt, wb);

  // out = [xi|w|u] @ [A|B1|B2]^T + bx   (K=704, N=512), 256x256 tile
  gemm2ph<256, 256, 2, 4><<<dim3(BSZ / 256, NXD / 256), 512, 0, stream>>>(
      xib, NXD, NXD, wb, NXD + NQD, NQD, ub, NUD, Wo, NXD + NQD + NUD, bx, out,
      NXD);
}

// Round 10
// 211.878 us; speedup vs baseline: 1.3557x; 1.0820x over previous
//
#include <hip/hip_runtime.h>
#include <hip/hip_bf16.h>

// Sizes fixed by the problem.
#define BSZ 32768
#define NXD 512
#define NQD 128
#define NUD 64

typedef __attribute__((ext_vector_type(8))) unsigned short u16x8;
typedef __attribute__((ext_vector_type(8))) __bf16 bf16x8;
typedef __attribute__((ext_vector_type(4))) float f32x4;

#define DEVINL static __device__ __forceinline__

DEVINL unsigned short f2bf(float x) {
  __bf16 h = (__bf16)x;
  return __builtin_bit_cast(unsigned short, h);
}

DEVINL void gload_lds16(const ushort* g, ushort* l) {
  __builtin_amdgcn_global_load_lds(
      (const __attribute__((address_space(1))) void*)g,
      (__attribute__((address_space(3))) void*)l, 16, 0, 0);
}

DEVINL bf16x8 ld_frag(const ushort* p) {
  return __builtin_bit_cast(bf16x8, *(const u16x8*)p);
}

// tanh(x) = 1 - 2/(exp2(x*2*log2e)+1). No clamp needed: exp2(+inf)->inf->rcp 0
// -> +1; exp2(-inf)->0 -> 1-2 = -1. 5 VALU ops (mul, exp, add, rcp, fma).
DEVINL float tanh_fast(float x) {
  float e2 = __builtin_amdgcn_exp2f(x * 2.88539008f);
  float r = __builtin_amdgcn_rcpf(e2 + 1.f);
  return __builtin_fmaf(-2.f, r, 1.f);
}

// ---------------------------------------------------------------------------
// prep: fused f32->bf16 converts + weight packing + D11 transpose.
//   xib[32768][512], ub[32768][64]           (bf16)
//   Wv[128][576]  row i = [C1[i] | D12[i]]   (bf16)
//   Wo[512][704]  row n = [A[n] | B1[n] | B2[n]] (bf16)
//   Dt[128][128]  Dt[j][i] = D11[i][j]       (f32, strictly upper)
// ---------------------------------------------------------------------------
DEVINL void cvt8(const float* src, ushort* dst, int i) {
  const float4* s = (const float4*)src;
  float4 a = s[i * 2], b = s[i * 2 + 1];
  u16x8 v;
  v[0] = f2bf(a.x); v[1] = f2bf(a.y); v[2] = f2bf(a.z); v[3] = f2bf(a.w);
  v[4] = f2bf(b.x); v[5] = f2bf(b.y); v[6] = f2bf(b.z); v[7] = f2bf(b.w);
  *(u16x8*)(dst + (size_t)i * 8) = v;
}

__global__ __launch_bounds__(256) void prep(
    const float* __restrict__ xi, const float* __restrict__ u,
    const float* __restrict__ A, const float* __restrict__ B1,
    const float* __restrict__ B2, const float* __restrict__ C1,
    const float* __restrict__ D11, const float* __restrict__ D12,
    ushort* __restrict__ xib, ushort* __restrict__ ub,
    ushort* __restrict__ Wv, ushort* __restrict__ Wo,
    float* __restrict__ Dt) {
  int idx = blockIdx.x * 256 + threadIdx.x;
  const int N0 = BSZ * NXD / 8;            // 2097152  xi convert (8-wide)
  const int N1 = N0 + BSZ * NUD / 8;       // + 262144 u convert (8-wide)
  const int N2 = N1 + NQD * (NXD + NUD);   // + 73728  Wv
  const int N3 = N2 + NXD * 704;           // + 360448 Wo
  const int N4 = N3 + NQD * NQD;           // + 16384  Dt
  if (idx < N0) {
    cvt8(xi, xib, idx);
  } else if (idx < N1) {
    cvt8(u, ub, idx - N0);
  } else if (idx < N2) {
    int f = idx - N1;
    int i = f / (NXD + NUD);
    int k = f - i * (NXD + NUD);
    Wv[f] = f2bf(k < NXD ? C1[i * NXD + k] : D12[i * NUD + (k - NXD)]);
  } else if (idx < N3) {
    int f = idx - N2;
    int n = f / 704;
    int k = f - n * 704;
    float v;
    if (k < NXD)            v = A[n * NXD + k];
    else if (k < NXD + NQD) v = B1[n * NQD + (k - NXD)];
    else                    v = B2[n * NUD + (k - NXD - NQD)];
    Wo[f] = f2bf(v);
  } else if (idx < N4) {
    int f = idx - N3;
    int j = f >> 7, i = f & (NQD - 1);
    Dt[f] = D11[i * NQD + j];
  }
}

// ---------------------------------------------------------------------------
// bf16 GEMM, 2-phase double-buffered, BK=64, T2 XOR-swizzled LDS.
//   out[M][N] = Mseg @ W^T + bias
//   A operand: up to 3 row-major bf16 segments concatenated along K
//     (all segment boundaries are multiples of BK=64).
//   W: [N][K] row-major bf16.
//   Swizzle (rule #21): LDS dest linear for global_load_lds; the global
//   SOURCE column is pre-permuted (slot ^ row&7), ds_read applies the same
//   XOR -> frag reads are 2-way conflicts (free).
// ---------------------------------------------------------------------------
template <int BM, int BN, int WM, int WN>
__global__ __launch_bounds__(WM* WN * 64, 2) void gemm2ph(
    const ushort* __restrict__ p0, int e0, int ld0,
    const ushort* __restrict__ p1, int e1, int ld1,
    const ushort* __restrict__ p2, int ld2,
    const ushort* __restrict__ W, int K,
    const float* __restrict__ biasN,
    float* __restrict__ out, int ldo) {
  constexpr int THREADS = WM * WN * 64;
  constexpr int BK = 64;
  constexpr int MREP = BM / WM / 16;
  constexpr int NREP = BN / WN / 16;
  constexpr int PASSA = BM * 8 / THREADS;
  constexpr int PASSB = BN * 8 / THREADS;

  __shared__ ushort ldsA[2][BM * BK];
  __shared__ ushort ldsB[2][BN * BK];

  const int tid = threadIdx.x;
  const int lane = tid & 63;
  const int wv = tid >> 6;
  const int wm = wv / WN, wn = wv % WN;
  const int rowBase = blockIdx.x * BM;
  const int colBase = blockIdx.y * BN;

  f32x4 acc[MREP][NREP];
#pragma unroll
  for (int m = 0; m < MREP; ++m)
#pragma unroll
    for (int n = 0; n < NREP; ++n) acc[m][n] = (f32x4){0.f, 0.f, 0.f, 0.f};

  const int NT = K / BK;

  auto stage = [&](int b, int kt) {
    const int k0 = kt * BK;
    const ushort* src; int kk, ld;
    if (k0 < e0)      { src = p0; kk = k0;      ld = ld0; }
    else if (k0 < e1) { src = p1; kk = k0 - e0; ld = ld1; }
    else              { src = p2; kk = k0 - e1; ld = ld2; }
#pragma unroll
    for (int p = 0; p < PASSA; ++p) {
      int idx = p * THREADS + tid;
      int row = idx >> 3, slot = idx & 7;
      int gcol = kk + ((slot ^ (row & 7)) << 3);
      gload_lds16(src + (size_t)(rowBase + row) * ld + gcol,
                  &ldsA[b][idx * 8]);
    }
#pragma unroll
    for (int p = 0; p < PASSB; ++p) {
      int idx = p * THREADS + tid;
      int row = idx >> 3, slot = idx & 7;
      int gcol = k0 + ((slot ^ (row & 7)) << 3);
      gload_lds16(W + (size_t)(colBase + row) * K + gcol, &ldsB[b][idx * 8]);
    }
  };

  stage(0, 0);
  __syncthreads();  // drains vmcnt -> buf0 ready

  int cur = 0;
  for (int kt = 0; kt < NT; ++kt) {
    if (kt + 1 < NT) stage(cur ^ 1, kt + 1);  // prefetch under compute

#pragma unroll
    for (int ks = 0; ks < 2; ++ks) {
      bf16x8 af[MREP], bfr[NREP];
#pragma unroll
      for (int m = 0; m < MREP; ++m) {
        int r = wm * (BM / WM) + m * 16 + (lane & 15);
        int slot = (ks * 4 + (lane >> 4)) ^ (r & 7);
        af[m] = ld_frag(&ldsA[cur][r * BK + slot * 8]);
      }
#pragma unroll
      for (int n = 0; n < NREP; ++n) {
        int r = wn * (BN / WN) + n * 16 + (lane & 15);
        int slot = (ks * 4 + (lane >> 4)) ^ (r & 7);
        bfr[n] = ld_frag(&ldsB[cur][r * BK + slot * 8]);
      }
#pragma unroll
      for (int m = 0; m < MREP; ++m)
#pragma unroll
        for (int n = 0; n < NREP; ++n)
          acc[m][n] = __builtin_amdgcn_mfma_f32_16x16x32_bf16(
              af[m], bfr[n], acc[m][n], 0, 0, 0);
    }
    __syncthreads();  // all reads of buf[cur] done; prefetch drained
    cur ^= 1;
  }

  const int cl = lane & 15;
  const int rq = (lane >> 4) * 4;
#pragma unroll
  for (int m = 0; m < MREP; ++m) {
    int row = rowBase + wm * (BM / WM) + m * 16 + rq;
#pragma unroll
    for (int n = 0; n < NREP; ++n) {
      int col = colBase + wn * (BN / WN) + n * 16 + cl;
      float bn = biasN[col];
      float* o = out + (size_t)row * ldo + col;
#pragma unroll
      for (int j = 0; j < 4; ++j) o[(size_t)j * ldo] = acc[m][n][j] + bn;
    }
  }
}

// ---------------------------------------------------------------------------
// Forward substitution, column-sweep, 8 lanes/row, chunk-strided ownership.
//   w[j] = tanh(acc[j]);  acc[i] += Dt[j][i]*w[j]  (Dt strictly upper)
// Lane s = lane&7 owns f32x4 chunks c = s+8k (k=0..3) -> i in [4c, 4c+4).
// Chunk k retires after step j = 32k+31 (all its i <= 32k+31 are done), so
// FMA/LDS work gets the triangular 0.625 factor with uniform-across-lane
// retirement. w is stored IN PLACE into acc (later steps add Dt[j'][j]=0).
// 8 rows/wave, 512 thr = 8 waves = 64 rows/block, grid 512 -> 4096 waves
// (4/SIMD). D in LDS plain row-major; 8 lanes read 8 consecutive 16B chunks
// (banks 0..31, conflict-free, 8-way group broadcast via ds_bpermute/__shfl).
// Full 128-step unroll: all acc indices compile-time.
// ---------------------------------------------------------------------------
__global__ __launch_bounds__(512) void recur8(const float* __restrict__ base,
                                              const float* __restrict__ Dt,
                                              ushort* __restrict__ wout) {
  __shared__ float ldsD[NQD * NQD];  // 64 KB, row-major [j][i]
  const int tid = threadIdx.x;
  for (int c = tid; c < NQD * NQD / 4; c += 512)
    ((float4*)ldsD)[c] = ((const float4*)Dt)[c];
  __syncthreads();

  const int lane = tid & 63;
  const int wid = tid >> 6;
  const int s = lane & 7;       // lane-in-group
  const int grp = lane >> 3;    // 8 groups of 8 lanes; 1 row per group
  const int row = blockIdx.x * 64 + wid * 8 + grp;
  const int laneBase = lane & 56;  // group base lane (for broadcast)

  // acc[k][e] <-> i = 4*(s + 8k) + e
  float4 acc[4];
  {
    const float4* bp4 = (const float4*)(base + (size_t)row * NQD);
#pragma unroll
    for (int k = 0; k < 4; ++k) acc[k] = bp4[s + 8 * k];
  }

  const float4* D4 = (const float4*)ldsD;

#pragma unroll
  for (int j = 0; j < NQD; ++j) {
    const int src = (j >> 2) & 7;   // owner lane-in-group of acc[j]
    const int r = j >> 5;           // owner's chunk reg
    const int e = j & 3;
    float tv = tanh_fast(acc[r][e]);  // real value on owner lane only
    // broadcast owner's tv to its 8-lane group (v_or + ds_bpermute)
    float wj = __shfl(tv, laneBase | src, 64);
    if (s == src) acc[r][e] = wj;   // w in place; later FMAs add Dt[j'][j]=0
#pragma unroll
    for (int k = 0; k < 4; ++k) {
      if (j < 32 * k + 32) {        // chunk retirement (compile-time)
        float4 d = D4[j * 32 + s + 8 * k];
        acc[k].x += d.x * wj; acc[k].y += d.y * wj;
        acc[k].z += d.z * wj; acc[k].w += d.w * wj;
      }
    }
  }

  // every acc slot was eventually overwritten by its w value
  ushort* orow = wout + (size_t)row * NQD;
#pragma unroll
  for (int k = 0; k < 4; ++k) {
    ushort4 v;
    v.x = f2bf(acc[k].x); v.y = f2bf(acc[k].y);
    v.z = f2bf(acc[k].z); v.w = f2bf(acc[k].w);
    *(ushort4*)(orow + 4 * (s + 8 * k)) = v;
  }
}

// ---------------------------------------------------------------------------
extern "C" void kernel_launch(void* const* d_in, const int* in_sizes, int n_in,
                              void* d_out, int out_size, void* d_ws, size_t ws_size,
                              hipStream_t stream) {
  const float* xi  = (const float*)d_in[0];
  const float* u   = (const float*)d_in[1];
  const float* A   = (const float*)d_in[2];
  const float* B1  = (const float*)d_in[3];
  const float* B2  = (const float*)d_in[4];
  const float* C1  = (const float*)d_in[5];
  const float* D11 = (const float*)d_in[6];
  const float* D12 = (const float*)d_in[7];
  const float* bx  = (const float*)d_in[8];
  const float* bv  = (const float*)d_in[9];
  float* out = (float*)d_out;

  char* ws = (char*)d_ws;
  ushort* xib  = (ushort*)(ws + 0);          // 32768*512*2  = 33554432
  ushort* ub   = (ushort*)(ws + 33554432);   // 32768*64*2   =  4194304
  ushort* wb   = (ushort*)(ws + 37748736);   // 32768*128*2  =  8388608
  float*  base = (float*)(ws + 46137344);    // 32768*128*4  = 16777216
  ushort* Wv   = (ushort*)(ws + 62914560);   // 128*576*2    =   147456
  ushort* Wo   = (ushort*)(ws + 63062016);   // 512*704*2    =   720896
  float*  Dt   = (float*)(ws + 63782912);    // 128*128*4    =    65536

  {
    int total = BSZ * NXD / 8 + BSZ * NUD / 8 + NQD * (NXD + NUD) + NXD * 704 +
                NQD * NQD;
    prep<<<dim3((total + 255) / 256), 256, 0, stream>>>(
        xi, u, A, B1, B2, C1, D11, D12, xib, ub, Wv, Wo, Dt);
  }

  // base = [xi|u] @ [C1|D12]^T + bv   (K=576, N=128), 128x128 tile
  gemm2ph<128, 128, 2, 2><<<dim3(BSZ / 128, 1), 256, 0, stream>>>(
      xib, NXD, NXD, ub, NXD + NUD, NUD, ub, NUD, Wv, NXD + NUD, bv, base, NQD);

  // w = forward substitution + tanh (8 lanes/row, chunk-strided, full unroll)
  recur8<<<dim3(BSZ / 64), 512, 0, stream>>>(base, Dt, wb);

  // out = [xi|w|u] @ [A|B1|B2]^T + bx   (K=704, N=512), 256x256 tile
  gemm2ph<256, 256, 2, 4><<<dim3(BSZ / 256, NXD / 256), 512, 0, stream>>>(
      xib, NXD, NXD, wb, NXD + NQD, NQD, ub, NUD, Wo, NXD + NQD + NUD, bx, out,
      NXD);
}

// Round 11
// 205.707 us; speedup vs baseline: 1.3964x; 1.0300x over previous
//
#include <hip/hip_runtime.h>
#include <hip/hip_bf16.h>

// Sizes fixed by the problem.
#define BSZ 32768
#define NXD 512
#define NQD 128
#define NUD 64

typedef __attribute__((ext_vector_type(8))) unsigned short u16x8;
typedef __attribute__((ext_vector_type(8))) __bf16 bf16x8;
typedef __attribute__((ext_vector_type(4))) float f32x4;

#define DEVINL static __device__ __forceinline__

DEVINL unsigned short f2bf(float x) {
  __bf16 h = (__bf16)x;
  return __builtin_bit_cast(unsigned short, h);
}

DEVINL void gload_lds16(const ushort* g, ushort* l) {
  __builtin_amdgcn_global_load_lds(
      (const __attribute__((address_space(1))) void*)g,
      (__attribute__((address_space(3))) void*)l, 16, 0, 0);
}

DEVINL bf16x8 ld_frag(const ushort* p) {
  return __builtin_bit_cast(bf16x8, *(const u16x8*)p);
}

// tanh(x) = 1 - 2/(exp2(x*2*log2e)+1). Saturates correctly at +/-inf.
DEVINL float tanh_fast(float x) {
  float e2 = __builtin_amdgcn_exp2f(x * 2.88539008f);
  float r = __builtin_amdgcn_rcpf(e2 + 1.f);
  return __builtin_fmaf(-2.f, r, 1.f);
}

// ---------------------------------------------------------------------------
// prep: fused f32->bf16 converts + weight packing + D11 transpose.
// ---------------------------------------------------------------------------
DEVINL void cvt8(const float* src, ushort* dst, int i) {
  const float4* s = (const float4*)src;
  float4 a = s[i * 2], b = s[i * 2 + 1];
  u16x8 v;
  v[0] = f2bf(a.x); v[1] = f2bf(a.y); v[2] = f2bf(a.z); v[3] = f2bf(a.w);
  v[4] = f2bf(b.x); v[5] = f2bf(b.y); v[6] = f2bf(b.z); v[7] = f2bf(b.w);
  *(u16x8*)(dst + (size_t)i * 8) = v;
}

__global__ __launch_bounds__(256) void prep(
    const float* __restrict__ xi, const float* __restrict__ u,
    const float* __restrict__ A, const float* __restrict__ B1,
    const float* __restrict__ B2, const float* __restrict__ C1,
    const float* __restrict__ D11, const float* __restrict__ D12,
    ushort* __restrict__ xib, ushort* __restrict__ ub,
    ushort* __restrict__ Wv, ushort* __restrict__ Wo,
    float* __restrict__ Dt) {
  int idx = blockIdx.x * 256 + threadIdx.x;
  const int N0 = BSZ * NXD / 8;            // xi convert (8-wide)
  const int N1 = N0 + BSZ * NUD / 8;       // u convert (8-wide)
  const int N2 = N1 + NQD * (NXD + NUD);   // Wv
  const int N3 = N2 + NXD * 704;           // Wo
  const int N4 = N3 + NQD * NQD;           // Dt
  if (idx < N0) {
    cvt8(xi, xib, idx);
  } else if (idx < N1) {
    cvt8(u, ub, idx - N0);
  } else if (idx < N2) {
    int f = idx - N1;
    int i = f / (NXD + NUD);
    int k = f - i * (NXD + NUD);
    Wv[f] = f2bf(k < NXD ? C1[i * NXD + k] : D12[i * NUD + (k - NXD)]);
  } else if (idx < N3) {
    int f = idx - N2;
    int n = f / 704;
    int k = f - n * 704;
    float v;
    if (k < NXD)            v = A[n * NXD + k];
    else if (k < NXD + NQD) v = B1[n * NQD + (k - NXD)];
    else                    v = B2[n * NUD + (k - NXD - NQD)];
    Wo[f] = f2bf(v);
  } else if (idx < N4) {
    int f = idx - N3;
    int j = f >> 7, i = f & (NQD - 1);
    Dt[f] = D11[i * NQD + j];
  }
}

// ---------------------------------------------------------------------------
// bf16 GEMM, m97 structure + T2 swizzle: 128x128 tile, BK=64, SINGLE LDS
// buffer (32 KB -> ~5 blocks/CU), 4 waves (2x2), 2 barriers/K-step.
// Cross-BLOCK wave overlap hides the barrier drains (m97/m114 mechanism) --
// this is what the 1-block/CU dbuf version lacked (Occupancy 16%).
//   out[M][N] = Mseg @ W^T + bias; A operand = up to 3 row-major bf16
//   segments along K (boundaries multiples of BK=64); W = [N][K] row-major.
//   Swizzle: linear LDS dest for global_load_lds + inverse-permuted global
//   source col (slot ^ row&7) + same XOR on ds_read -> <=2-way (free, 
//   measured 0 conflicts in R10).
// ---------------------------------------------------------------------------
template <int BM, int BN>
__global__ __launch_bounds__(256, 4) void gemm97(
    const ushort* __restrict__ p0, int e0, int ld0,
    const ushort* __restrict__ p1, int e1, int ld1,
    const ushort* __restrict__ p2, int ld2,
    const ushort* __restrict__ W, int K,
    const float* __restrict__ biasN,
    float* __restrict__ out, int ldo) {
  constexpr int THREADS = 256;
  constexpr int BK = 64;
  constexpr int MREP = BM / 2 / 16;   // 4
  constexpr int NREP = BN / 2 / 16;   // 4
  constexpr int PASSA = BM * 8 / THREADS;  // 4
  constexpr int PASSB = BN * 8 / THREADS;  // 4

  __shared__ ushort ldsA[BM * BK];  // 16 KB
  __shared__ ushort ldsB[BN * BK];  // 16 KB

  const int tid = threadIdx.x;
  const int lane = tid & 63;
  const int wv = tid >> 6;
  const int wm = wv >> 1, wn = wv & 1;
  const int rowBase = blockIdx.x * BM;
  const int colBase = blockIdx.y * BN;

  f32x4 acc[MREP][NREP];
#pragma unroll
  for (int m = 0; m < MREP; ++m)
#pragma unroll
    for (int n = 0; n < NREP; ++n) acc[m][n] = (f32x4){0.f, 0.f, 0.f, 0.f};

  const int NT = K / BK;

  for (int kt = 0; kt < NT; ++kt) {
    const int k0 = kt * BK;
    // segment select (wave-uniform)
    const ushort* src; int kk, ld;
    if (k0 < e0)      { src = p0; kk = k0;      ld = ld0; }
    else if (k0 < e1) { src = p1; kk = k0 - e0; ld = ld1; }
    else              { src = p2; kk = k0 - e1; ld = ld2; }

    // stage A+B K-tiles (linear LDS dest; pre-swizzled global source col)
#pragma unroll
    for (int p = 0; p < PASSA; ++p) {
      int idx = p * THREADS + tid;
      int row = idx >> 3, slot = idx & 7;
      int gcol = kk + ((slot ^ (row & 7)) << 3);
      gload_lds16(src + (size_t)(rowBase + row) * ld + gcol, &ldsA[idx * 8]);
    }
#pragma unroll
    for (int p = 0; p < PASSB; ++p) {
      int idx = p * THREADS + tid;
      int row = idx >> 3, slot = idx & 7;
      int gcol = k0 + ((slot ^ (row & 7)) << 3);
      gload_lds16(W + (size_t)(colBase + row) * K + gcol, &ldsB[idx * 8]);
    }
    __syncthreads();  // drains vmcnt -> tiles ready

#pragma unroll
    for (int ks = 0; ks < 2; ++ks) {
      bf16x8 af[MREP], bfr[NREP];
#pragma unroll
      for (int m = 0; m < MREP; ++m) {
        int r = wm * (BM / 2) + m * 16 + (lane & 15);
        int slot = (ks * 4 + (lane >> 4)) ^ (r & 7);
        af[m] = ld_frag(&ldsA[r * BK + slot * 8]);
      }
#pragma unroll
      for (int n = 0; n < NREP; ++n) {
        int r = wn * (BN / 2) + n * 16 + (lane & 15);
        int slot = (ks * 4 + (lane >> 4)) ^ (r & 7);
        bfr[n] = ld_frag(&ldsB[r * BK + slot * 8]);
      }
#pragma unroll
      for (int m = 0; m < MREP; ++m)
#pragma unroll
        for (int n = 0; n < NREP; ++n)
          acc[m][n] = __builtin_amdgcn_mfma_f32_16x16x32_bf16(
              af[m], bfr[n], acc[m][n], 0, 0, 0);
    }
    __syncthreads();  // all reads done -> next stage may overwrite
  }

  // epilogue: C/D layout col=lane&15, row=(lane>>4)*4+j
  const int cl = lane & 15;
  const int rq = (lane >> 4) * 4;
#pragma unroll
  for (int m = 0; m < MREP; ++m) {
    int row = rowBase + wm * (BM / 2) + m * 16 + rq;
#pragma unroll
    for (int n = 0; n < NREP; ++n) {
      int col = colBase + wn * (BN / 2) + n * 16 + cl;
      float bn = biasN[col];
      float* o = out + (size_t)row * ldo + col;
#pragma unroll
      for (int j = 0; j < 4; ++j) o[(size_t)j * ldo] = acc[m][n][j] + bn;
    }
  }
}

// ---------------------------------------------------------------------------
// Forward substitution, column-sweep, 8 lanes/row, chunk-strided ownership.
// (unchanged from R10 -- proven: <40 us, 0 conflicts)
// ---------------------------------------------------------------------------
__global__ __launch_bounds__(512) void recur8(const float* __restrict__ base,
                                              const float* __restrict__ Dt,
                                              ushort* __restrict__ wout) {
  __shared__ float ldsD[NQD * NQD];  // 64 KB, row-major [j][i]
  const int tid = threadIdx.x;
  for (int c = tid; c < NQD * NQD / 4; c += 512)
    ((float4*)ldsD)[c] = ((const float4*)Dt)[c];
  __syncthreads();

  const int lane = tid & 63;
  const int wid = tid >> 6;
  const int s = lane & 7;       // lane-in-group
  const int grp = lane >> 3;    // 8 groups of 8 lanes; 1 row per group
  const int row = blockIdx.x * 64 + wid * 8 + grp;
  const int laneBase = lane & 56;  // group base lane (for broadcast)

  // acc[k][e] <-> i = 4*(s + 8k) + e
  float4 acc[4];
  {
    const float4* bp4 = (const float4*)(base + (size_t)row * NQD);
#pragma unroll
    for (int k = 0; k < 4; ++k) acc[k] = bp4[s + 8 * k];
  }

  const float4* D4 = (const float4*)ldsD;

#pragma unroll
  for (int j = 0; j < NQD; ++j) {
    const int src = (j >> 2) & 7;   // owner lane-in-group of acc[j]
    const int r = j >> 5;           // owner's chunk reg
    const int e = j & 3;
    float tv = tanh_fast(acc[r][e]);  // real value on owner lane only
    float wj = __shfl(tv, laneBase | src, 64);
    if (s == src) acc[r][e] = wj;   // w in place; later FMAs add Dt[j'][j]=0
#pragma unroll
    for (int k = 0; k < 4; ++k) {
      if (j < 32 * k + 32) {        // chunk retirement (compile-time)
        float4 d = D4[j * 32 + s + 8 * k];
        acc[k].x += d.x * wj; acc[k].y += d.y * wj;
        acc[k].z += d.z * wj; acc[k].w += d.w * wj;
      }
    }
  }

  ushort* orow = wout + (size_t)row * NQD;
#pragma unroll
  for (int k = 0; k < 4; ++k) {
    ushort4 v;
    v.x = f2bf(acc[k].x); v.y = f2bf(acc[k].y);
    v.z = f2bf(acc[k].z); v.w = f2bf(acc[k].w);
    *(ushort4*)(orow + 4 * (s + 8 * k)) = v;
  }
}

// ---------------------------------------------------------------------------
extern "C" void kernel_launch(void* const* d_in, const int* in_sizes, int n_in,
                              void* d_out, int out_size, void* d_ws, size_t ws_size,
                              hipStream_t stream) {
  const float* xi  = (const float*)d_in[0];
  const float* u   = (const float*)d_in[1];
  const float* A   = (const float*)d_in[2];
  const float* B1  = (const float*)d_in[3];
  const float* B2  = (const float*)d_in[4];
  const float* C1  = (const float*)d_in[5];
  const float* D11 = (const float*)d_in[6];
  const float* D12 = (const float*)d_in[7];
  const float* bx  = (const float*)d_in[8];
  const float* bv  = (const float*)d_in[9];
  float* out = (float*)d_out;

  char* ws = (char*)d_ws;
  ushort* xib  = (ushort*)(ws + 0);          // 32768*512*2  = 33554432
  ushort* ub   = (ushort*)(ws + 33554432);   // 32768*64*2   =  4194304
  ushort* wb   = (ushort*)(ws + 37748736);   // 32768*128*2  =  8388608
  float*  base = (float*)(ws + 46137344);    // 32768*128*4  = 16777216
  ushort* Wv   = (ushort*)(ws + 62914560);   // 128*576*2    =   147456
  ushort* Wo   = (ushort*)(ws + 63062016);   // 512*704*2    =   720896
  float*  Dt   = (float*)(ws + 63782912);    // 128*128*4    =    65536

  {
    int total = BSZ * NXD / 8 + BSZ * NUD / 8 + NQD * (NXD + NUD) + NXD * 704 +
                NQD * NQD;
    prep<<<dim3((total + 255) / 256), 256, 0, stream>>>(
        xi, u, A, B1, B2, C1, D11, D12, xib, ub, Wv, Wo, Dt);
  }

  // base = [xi|u] @ [C1|D12]^T + bv   (K=576, N=128)
  gemm97<128, 128><<<dim3(BSZ / 128, 1), 256, 0, stream>>>(
      xib, NXD, NXD, ub, NXD + NUD, NUD, ub, NUD, Wv, NXD + NUD, bv, base, NQD);

  // w = forward substitution + tanh (8 lanes/row, chunk-strided, full unroll)
  recur8<<<dim3(BSZ / 64), 512, 0, stream>>>(base, Dt, wb);

  // out = [xi|w|u] @ [A|B1|B2]^T + bx   (K=704, N=512)
  gemm97<128, 128><<<dim3(BSZ / 128, NXD / 128), 256, 0, stream>>>(
      xib, NXD, NXD, wb, NXD + NQD, NQD, ub, NUD, Wo, NXD + NQD + NUD, bx, out,
      NXD);
}

// Round 12
// 204.277 us; speedup vs baseline: 1.4061x; 1.0070x over previous
//
#include <hip/hip_runtime.h>
#include <hip/hip_bf16.h>

// Sizes fixed by the problem.
#define BSZ 32768
#define NXD 512
#define NQD 128
#define NUD 64

typedef __attribute__((ext_vector_type(8))) unsigned short u16x8;
typedef __attribute__((ext_vector_type(8))) __bf16 bf16x8;
typedef __attribute__((ext_vector_type(4))) float f32x4;

#define DEVINL static __device__ __forceinline__

DEVINL unsigned short f2bf(float x) {
  __bf16 h = (__bf16)x;
  return __builtin_bit_cast(unsigned short, h);
}

DEVINL void gload_lds16(const ushort* g, ushort* l) {
  __builtin_amdgcn_global_load_lds(
      (const __attribute__((address_space(1))) void*)g,
      (__attribute__((address_space(3))) void*)l, 16, 0, 0);
}

DEVINL bf16x8 ld_frag(const ushort* p) {
  return __builtin_bit_cast(bf16x8, *(const u16x8*)p);
}

// tanh(x) = 1 - 2/(exp2(x*2*log2e)+1). Saturates correctly at +/-inf.
DEVINL float tanh_fast(float x) {
  float e2 = __builtin_amdgcn_exp2f(x * 2.88539008f);
  float r = __builtin_amdgcn_rcpf(e2 + 1.f);
  return __builtin_fmaf(-2.f, r, 1.f);
}

// ---------------------------------------------------------------------------
// prep: fused f32->bf16 converts + weight packing + D11 transpose.
// (unchanged from R11)
// ---------------------------------------------------------------------------
DEVINL void cvt8(const float* src, ushort* dst, int i) {
  const float4* s = (const float4*)src;
  float4 a = s[i * 2], b = s[i * 2 + 1];
  u16x8 v;
  v[0] = f2bf(a.x); v[1] = f2bf(a.y); v[2] = f2bf(a.z); v[3] = f2bf(a.w);
  v[4] = f2bf(b.x); v[5] = f2bf(b.y); v[6] = f2bf(b.z); v[7] = f2bf(b.w);
  *(u16x8*)(dst + (size_t)i * 8) = v;
}

__global__ __launch_bounds__(256) void prep(
    const float* __restrict__ xi, const float* __restrict__ u,
    const float* __restrict__ A, const float* __restrict__ B1,
    const float* __restrict__ B2, const float* __restrict__ C1,
    const float* __restrict__ D11, const float* __restrict__ D12,
    ushort* __restrict__ xib, ushort* __restrict__ ub,
    ushort* __restrict__ Wv, ushort* __restrict__ Wo,
    float* __restrict__ Dt) {
  int idx = blockIdx.x * 256 + threadIdx.x;
  const int N0 = BSZ * NXD / 8;            // xi convert (8-wide)
  const int N1 = N0 + BSZ * NUD / 8;       // u convert (8-wide)
  const int N2 = N1 + NQD * (NXD + NUD);   // Wv
  const int N3 = N2 + NXD * 704;           // Wo
  const int N4 = N3 + NQD * NQD;           // Dt
  if (idx < N0) {
    cvt8(xi, xib, idx);
  } else if (idx < N1) {
    cvt8(u, ub, idx - N0);
  } else if (idx < N2) {
    int f = idx - N1;
    int i = f / (NXD + NUD);
    int k = f - i * (NXD + NUD);
    Wv[f] = f2bf(k < NXD ? C1[i * NXD + k] : D12[i * NUD + (k - NXD)]);
  } else if (idx < N3) {
    int f = idx - N2;
    int n = f / 704;
    int k = f - n * 704;
    float v;
    if (k < NXD)            v = A[n * NXD + k];
    else if (k < NXD + NQD) v = B1[n * NQD + (k - NXD)];
    else                    v = B2[n * NUD + (k - NXD - NQD)];
    Wo[f] = f2bf(v);
  } else if (idx < N4) {
    int f = idx - N3;
    int j = f >> 7, i = f & (NQD - 1);
    Dt[f] = D11[i * NQD + j];
  }
}

// ---------------------------------------------------------------------------
// bf16 GEMM, m97 structure + T2 swizzle: 128x128 tile, BK=64, single LDS
// buffer (32 KB), 4 waves, 2 barriers/K-step. (unchanged from R11 -- proven)
// ---------------------------------------------------------------------------
template <int BM, int BN>
__global__ __launch_bounds__(256, 4) void gemm97(
    const ushort* __restrict__ p0, int e0, int ld0,
    const ushort* __restrict__ p1, int e1, int ld1,
    const ushort* __restrict__ p2, int ld2,
    const ushort* __restrict__ W, int K,
    const float* __restrict__ biasN,
    float* __restrict__ out, int ldo) {
  constexpr int THREADS = 256;
  constexpr int BK = 64;
  constexpr int MREP = BM / 2 / 16;   // 4
  constexpr int NREP = BN / 2 / 16;   // 4
  constexpr int PASSA = BM * 8 / THREADS;  // 4
  constexpr int PASSB = BN * 8 / THREADS;  // 4

  __shared__ ushort ldsA[BM * BK];  // 16 KB
  __shared__ ushort ldsB[BN * BK];  // 16 KB

  const int tid = threadIdx.x;
  const int lane = tid & 63;
  const int wv = tid >> 6;
  const int wm = wv >> 1, wn = wv & 1;
  const int rowBase = blockIdx.x * BM;
  const int colBase = blockIdx.y * BN;

  f32x4 acc[MREP][NREP];
#pragma unroll
  for (int m = 0; m < MREP; ++m)
#pragma unroll
    for (int n = 0; n < NREP; ++n) acc[m][n] = (f32x4){0.f, 0.f, 0.f, 0.f};

  const int NT = K / BK;

  for (int kt = 0; kt < NT; ++kt) {
    const int k0 = kt * BK;
    const ushort* src; int kk, ld;
    if (k0 < e0)      { src = p0; kk = k0;      ld = ld0; }
    else if (k0 < e1) { src = p1; kk = k0 - e0; ld = ld1; }
    else              { src = p2; kk = k0 - e1; ld = ld2; }

#pragma unroll
    for (int p = 0; p < PASSA; ++p) {
      int idx = p * THREADS + tid;
      int row = idx >> 3, slot = idx & 7;
      int gcol = kk + ((slot ^ (row & 7)) << 3);
      gload_lds16(src + (size_t)(rowBase + row) * ld + gcol, &ldsA[idx * 8]);
    }
#pragma unroll
    for (int p = 0; p < PASSB; ++p) {
      int idx = p * THREADS + tid;
      int row = idx >> 3, slot = idx & 7;
      int gcol = k0 + ((slot ^ (row & 7)) << 3);
      gload_lds16(W + (size_t)(colBase + row) * K + gcol, &ldsB[idx * 8]);
    }
    __syncthreads();  // drains vmcnt -> tiles ready

#pragma unroll
    for (int ks = 0; ks < 2; ++ks) {
      bf16x8 af[MREP], bfr[NREP];
#pragma unroll
      for (int m = 0; m < MREP; ++m) {
        int r = wm * (BM / 2) + m * 16 + (lane & 15);
        int slot = (ks * 4 + (lane >> 4)) ^ (r & 7);
        af[m] = ld_frag(&ldsA[r * BK + slot * 8]);
      }
#pragma unroll
      for (int n = 0; n < NREP; ++n) {
        int r = wn * (BN / 2) + n * 16 + (lane & 15);
        int slot = (ks * 4 + (lane >> 4)) ^ (r & 7);
        bfr[n] = ld_frag(&ldsB[r * BK + slot * 8]);
      }
#pragma unroll
      for (int m = 0; m < MREP; ++m)
#pragma unroll
        for (int n = 0; n < NREP; ++n)
          acc[m][n] = __builtin_amdgcn_mfma_f32_16x16x32_bf16(
              af[m], bfr[n], acc[m][n], 0, 0, 0);
    }
    __syncthreads();  // all reads done -> next stage may overwrite
  }

  const int cl = lane & 15;
  const int rq = (lane >> 4) * 4;
#pragma unroll
  for (int m = 0; m < MREP; ++m) {
    int row = rowBase + wm * (BM / 2) + m * 16 + rq;
#pragma unroll
    for (int n = 0; n < NREP; ++n) {
      int col = colBase + wn * (BN / 2) + n * 16 + cl;
      float bn = biasN[col];
      float* o = out + (size_t)row * ldo + col;
#pragma unroll
      for (int j = 0; j < 4; ++j) o[(size_t)j * ldo] = acc[m][n][j] + bn;
    }
  }
}

// ---------------------------------------------------------------------------
// Forward substitution, column-sweep, 8 lanes/row, chunk-strided ownership,
// 4-SEGMENT LOOPED body (I-cache-friendly; ~500 instr vs 128-unroll's ~25KB).
// Segment seg covers j in [32seg, 32seg+32): tanh/w-slot register = 
// acc[seg][jj&3] (compile-time), active chunk regs k = seg..3 (compile-time,
// since retirement j=32k+32 aligns with segment boundaries). jb runtime.
//   w[j] = tanh(acc[j]);  acc[i] += Dt[j][i]*w[j]  (Dt strictly upper)
// Lane s=lane&7 owns chunks c=s+8k; 8 rows/wave; in-place w (diag zeros).
// ---------------------------------------------------------------------------
__global__ __launch_bounds__(512, 4) void recur8b(const float* __restrict__ base,
                                                  const float* __restrict__ Dt,
                                                  ushort* __restrict__ wout) {
  __shared__ float ldsD[NQD * NQD];  // 64 KB, row-major [j][i]
  const int tid = threadIdx.x;
  for (int c = tid; c < NQD * NQD / 4; c += 512)
    ((float4*)ldsD)[c] = ((const float4*)Dt)[c];
  __syncthreads();

  const int lane = tid & 63;
  const int wid = tid >> 6;
  const int s = lane & 7;          // lane-in-group
  const int grp = lane >> 3;       // 8 groups; 1 batch row per group
  const int row = blockIdx.x * 64 + wid * 8 + grp;
  const int laneBase = lane & 56;

  // acc[k][e] <-> i = 4*(s + 8k) + e
  float4 acc[4];
  {
    const float4* bp4 = (const float4*)(base + (size_t)row * NQD);
#pragma unroll
    for (int k = 0; k < 4; ++k) acc[k] = bp4[s + 8 * k];
  }

  const float4* D4 = (const float4*)ldsD;

  // ---- segment macro: seg = compile-time; jb runtime over 4 iterations ----
#define SEGMENT(SEG)                                                          \
  for (int jb = 4 * SEG; jb < 4 * SEG + 4; ++jb) {                            \
    _Pragma("unroll")                                                         \
    for (int jj = 0; jj < 8; ++jj) {                                          \
      const int e = jj & 3;             /* compile-time reg element */        \
      const int j = jb * 8 + jj;        /* runtime scalar */                  \
      float tv = tanh_fast(acc[SEG][e]);                                      \
      int src = (j >> 2) & 7;                                                 \
      float wj = __shfl(tv, laneBase | src, 64);                              \
      if (s == src) acc[SEG][e] = wj;                                         \
      const int jrow = j * 32;                                                \
      _Pragma("unroll")                                                       \
      for (int k = SEG; k < 4; ++k) {                                         \
        float4 d = D4[jrow + s + 8 * k];                                      \
        acc[k].x += d.x * wj; acc[k].y += d.y * wj;                           \
        acc[k].z += d.z * wj; acc[k].w += d.w * wj;                           \
      }                                                                       \
    }                                                                         \
  }

  SEGMENT(0)
  SEGMENT(1)
  SEGMENT(2)
  SEGMENT(3)
#undef SEGMENT

  // every acc slot was overwritten by its w value during its segment
  ushort* orow = wout + (size_t)row * NQD;
#pragma unroll
  for (int k = 0; k < 4; ++k) {
    ushort4 v;
    v.x = f2bf(acc[k].x); v.y = f2bf(acc[k].y);
    v.z = f2bf(acc[k].z); v.w = f2bf(acc[k].w);
    *(ushort4*)(orow + 4 * (s + 8 * k)) = v;
  }
}

// ---------------------------------------------------------------------------
extern "C" void kernel_launch(void* const* d_in, const int* in_sizes, int n_in,
                              void* d_out, int out_size, void* d_ws, size_t ws_size,
                              hipStream_t stream) {
  const float* xi  = (const float*)d_in[0];
  const float* u   = (const float*)d_in[1];
  const float* A   = (const float*)d_in[2];
  const float* B1  = (const float*)d_in[3];
  const float* B2  = (const float*)d_in[4];
  const float* C1  = (const float*)d_in[5];
  const float* D11 = (const float*)d_in[6];
  const float* D12 = (const float*)d_in[7];
  const float* bx  = (const float*)d_in[8];
  const float* bv  = (const float*)d_in[9];
  float* out = (float*)d_out;

  char* ws = (char*)d_ws;
  ushort* xib  = (ushort*)(ws + 0);          // 32768*512*2  = 33554432
  ushort* ub   = (ushort*)(ws + 33554432);   // 32768*64*2   =  4194304
  ushort* wb   = (ushort*)(ws + 37748736);   // 32768*128*2  =  8388608
  float*  base = (float*)(ws + 46137344);    // 32768*128*4  = 16777216
  ushort* Wv   = (ushort*)(ws + 62914560);   // 128*576*2    =   147456
  ushort* Wo   = (ushort*)(ws + 63062016);   // 512*704*2    =   720896
  float*  Dt   = (float*)(ws + 63782912);    // 128*128*4    =    65536

  {
    int total = BSZ * NXD / 8 + BSZ * NUD / 8 + NQD * (NXD + NUD) + NXD * 704 +
                NQD * NQD;
    prep<<<dim3((total + 255) / 256), 256, 0, stream>>>(
        xi, u, A, B1, B2, C1, D11, D12, xib, ub, Wv, Wo, Dt);
  }

  // base = [xi|u] @ [C1|D12]^T + bv   (K=576, N=128)
  gemm97<128, 128><<<dim3(BSZ / 128, 1), 256, 0, stream>>>(
      xib, NXD, NXD, ub, NXD + NUD, NUD, ub, NUD, Wv, NXD + NUD, bv, base, NQD);

  // w = forward substitution + tanh (8 lanes/row, 4-segment looped body)
  recur8b<<<dim3(BSZ / 64), 512, 0, stream>>>(base, Dt, wb);

  // out = [xi|w|u] @ [A|B1|B2]^T + bx   (K=704, N=512)
  gemm97<128, 128><<<dim3(BSZ / 128, NXD / 128), 256, 0, stream>>>(
      xib, NXD, NXD, wb, NXD + NQD, NQD, ub, NUD, Wo, NXD + NQD + NUD, bx, out,
      NXD);
}